// Round 3
// baseline (835.874 us; speedup 1.0000x reference)
//
#include <hip/hip_runtime.h>
#include <math.h>

// MoE gate: logits = X[T,4096] @ W^T[4096,64]; softmax over 64; top-2.
// Output layout (float32): [T*2] indices-as-float, then [T*2] weights.
//
// R3: (a) single-barrier double-buffered K-loop — the loop-top barrier's
// vmcnt(0) drain lands on a prefetch issued one full compute phase earlier,
// so HBM latency hides behind the 2048-cyc FMA phase (R2 showed 45% idle
// from the stage->barrier->compute structure at 2 blocks/CU).
// (b) hoisted swizzle addressing: per-thread float4 bases + shared (k4^tr)
// term, so the 8 ds_read_b128 per k4 use immediate offsets (R2 VALUBusy
// decomposition showed ~70% non-FMA VALU issue).
//
// LDS: 2 x (4096+4096) floats = 64 KB/block; 2 blocks/CU (grid-limited).
// Swizzle: slot = k4 ^ (row>>2) at float4 granularity -> <=2-way bank
// aliasing on ds_read_b128 (free, m136); staging stays base + lane*16 as
// global_load_lds requires (m104).

__device__ __forceinline__ void gl_lds16(const float* g, float* l) {
  __builtin_amdgcn_global_load_lds(
      (const __attribute__((address_space(1))) unsigned int*)g,
      (__attribute__((address_space(3))) unsigned int*)l,
      16, 0, 0);
}

__global__ __launch_bounds__(256)
void moe_gate(const float* __restrict__ X, const float* __restrict__ W,
              float* __restrict__ out, int T) {
  __shared__ float smem[16384];   // buf0: [0,8192) = sx|sw ; buf1: [8192,16384)

  const int t    = threadIdx.x;
  const int lane = t & 63;
  const int wave = t >> 6;
  const int tr   = t & 15;   // token-group  (tokens tr*4 .. tr*4+3)
  const int tc   = t >> 4;   // expert-group (experts tc*4 .. tc*4+3)
  const long tok0 = (long)blockIdx.x * 64;

  // --- staging pointers ---
  const float* xg[4];
  const float* wg[4];
  int lofs[4];                       // LDS float-offset within a buffer half
  {
    const int rl = lane >> 4;        // 0..3 row-within-instruction
    const int c4 = lane & 15;        // float4 slot 0..15
    #pragma unroll
    for (int i = 0; i < 4; ++i) {
      const int r  = wave * 16 + i * 4 + rl;   // tile row 0..63
      const int sz = (wave * 4 + i) & 15;      // = r>>2 (lane-invariant)
      const int gc = c4 ^ sz;                  // swizzled global col4
      xg[i] = X + (tok0 + r) * 4096 + gc * 4;
      wg[i] = W + (long)r * 4096 + gc * 4;
      lofs[i] = (wave * 16 + i * 4) * 64;      // wave-uniform
    }
  }

  float acc[4][4];
  #pragma unroll
  for (int i = 0; i < 4; ++i)
    #pragma unroll
    for (int j = 0; j < 4; ++j) acc[i][j] = 0.f;

  // prologue: stage chunk 0 into buf0
  #pragma unroll
  for (int i = 0; i < 4; ++i) {
    gl_lds16(xg[i], smem + lofs[i]);
    gl_lds16(wg[i], smem + 4096 + lofs[i]);
  }

  for (int c = 0; c < 64; ++c) {
    __syncthreads();   // drains last iter's prefetch (already ~arrived) +
                       // guards buffer reuse
    const int cur = c & 1;
    if (c + 1 < 64) {
      const int nxt = cur ^ 1;
      float* dst = smem + nxt * 8192;
      const long k0 = (long)(c + 1) * 64;
      #pragma unroll
      for (int i = 0; i < 4; ++i) {
        gl_lds16(xg[i] + k0, dst + lofs[i]);
        gl_lds16(wg[i] + k0, dst + 4096 + lofs[i]);
      }
    }

    const float4* xb = (const float4*)(smem + cur * 8192) + tr * 64;
    const float4* wb4 = (const float4*)(smem + cur * 8192 + 4096) + tc * 64;

    // chunk-local accumulator bounds fp32 rounding (~1e-6) so top-2 index
    // decisions match the reference accumulation order closely.
    float cacc[4][4];
    #pragma unroll
    for (int i = 0; i < 4; ++i)
      #pragma unroll
      for (int j = 0; j < 4; ++j) cacc[i][j] = 0.f;

    #pragma unroll
    for (int k4 = 0; k4 < 16; ++k4) {
      const int sx4 = k4 ^ tr;   // shared swizzled slot for this thread's rows
      const int sw4 = k4 ^ tc;
      float4 xa[4], wb[4];
      #pragma unroll
      for (int i = 0; i < 4; ++i) xa[i] = xb[i * 16 + sx4];   // imm offset i*256B
      #pragma unroll
      for (int j = 0; j < 4; ++j) wb[j] = wb4[j * 16 + sw4];
      #pragma unroll
      for (int i = 0; i < 4; ++i)
        #pragma unroll
        for (int j = 0; j < 4; ++j) {
          cacc[i][j] = fmaf(xa[i].x, wb[j].x, cacc[i][j]);
          cacc[i][j] = fmaf(xa[i].y, wb[j].y, cacc[i][j]);
          cacc[i][j] = fmaf(xa[i].z, wb[j].z, cacc[i][j]);
          cacc[i][j] = fmaf(xa[i].w, wb[j].w, cacc[i][j]);
        }
    }
    #pragma unroll
    for (int i = 0; i < 4; ++i)
      #pragma unroll
      for (int j = 0; j < 4; ++j) acc[i][j] += cacc[i][j];
  }

  // --- epilogue: logits -> LDS [64][65] in buf0 region ---
  // Last compute read buf1; all waves passed the c=63 barrier after their
  // final buf0 read, so buf0 is safe to overwrite here.
  #pragma unroll
  for (int i = 0; i < 4; ++i)
    #pragma unroll
    for (int j = 0; j < 4; ++j)
      smem[(tr * 4 + i) * 65 + tc * 4 + j] = acc[i][j];
  __syncthreads();

  if (t < 64) {
    const float* row = smem + t * 65;
    // strict '>' = stable lowest-index-first on ties, matching lax.top_k
    float b1 = -1e30f, b2 = -1e30f;
    int i1 = 0, i2 = 0;
    for (int e = 0; e < 64; ++e) {
      const float v = row[e];
      if (v > b1)      { b2 = b1; i2 = i1; b1 = v; i1 = e; }
      else if (v > b2) { b2 = v; i2 = e; }
    }
    float s = 0.f;
    for (int e = 0; e < 64; ++e) s += expf(row[e] - b1);
    const float inv = 1.0f / s;
    const long gt = tok0 + t;
    out[gt * 2 + 0] = (float)i1;
    out[gt * 2 + 1] = (float)i2;
    float* ow = out + (long)T * 2;
    ow[gt * 2 + 0] = inv;                 // exp(b1-b1)/s
    ow[gt * 2 + 1] = expf(b2 - b1) * inv;
  }
}

extern "C" void kernel_launch(void* const* d_in, const int* in_sizes, int n_in,
                              void* d_out, int out_size, void* d_ws, size_t ws_size,
                              hipStream_t stream) {
  const float* X = (const float*)d_in[0];   // [4,8192,4096] fp32
  const float* W = (const float*)d_in[1];   // [64,4096] fp32
  float* out = (float*)d_out;               // [T*2] idx-as-float, [T*2] weights
  const int T = in_sizes[0] / 4096;         // 32768 tokens
  const int grid = T / 64;                  // 512 workgroups = 2 blocks/CU
  hipLaunchKernelGGL(moe_gate, dim3(grid), dim3(256), 0, stream, X, W, out, T);
}